// Round 2
// baseline (989.640 us; speedup 1.0000x reference)
//
#include <hip/hip_runtime.h>
#include <cstdint>
#include <cstddef>

// Problem constants
#define OBS_DIMM 128
#define PROJJ    64
#define HIDD     256
#define LATT     24
#define BBATCH   1024
#define TTIME    256
#define KDIM     384   // 128 obs-cols + 256 h-cols
#define NGATE    768   // 3*HID
#define MBLK     32    // batches per block
#define CHUNK    32    // timesteps per block
#define XSTRIDE  392   // 384 + 8 pad (bf16 elems)
#define MSTRIDE  264   // 256 + 8 pad

using bf16x8 = __attribute__((ext_vector_type(8))) short;   // 8 bf16 in 4 VGPRs
using f32x4  = __attribute__((ext_vector_type(4))) float;
using f32x4v = __attribute__((ext_vector_type(4))) float;

static __device__ __forceinline__ unsigned short f2bf(float f) {
    unsigned u = __builtin_bit_cast(unsigned, f);
    u += 0x7fffu + ((u >> 16) & 1u);          // RNE
    return (unsigned short)(u >> 16);
}
static __device__ __forceinline__ float bf2f(unsigned short h) {
    return __builtin_bit_cast(float, ((unsigned)h) << 16);
}
static __device__ __forceinline__ float fexp2(float x) { return __builtin_amdgcn_exp2f(x); }
static __device__ __forceinline__ float flog2(float x) { return __builtin_amdgcn_logf(x); }
static __device__ __forceinline__ float frcp (float x) { return __builtin_amdgcn_rcpf(x); }
static __device__ __forceinline__ float sigmoid_(float x) { return frcp(1.f + fexp2(-1.44269504f * x)); }
static __device__ __forceinline__ float tanh_(float x)    { return 1.f - 2.f * frcp(fexp2(2.88539008f * x) + 1.f); }

#define MFMA16(a, b, c) __builtin_amdgcn_mfma_f32_16x16x32_bf16((a), (b), (c), 0, 0, 0)

// ---------------------------------------------------------------------------
// Prep: build fused weight W' = [[W_in@W_ih],[W_hh]] (384x768) in a PER-WAVE
// CONTIGUOUS stream layout: wave w's 72 KB is sequential in exact access order
//   idx = ((w*12 + ks)*6 + i*3 + gate)*512 + lane*8 + jj
// (wave w owns hidden units [32w,32w+32): col n = gate*256 + (2w+i)*16 + c16,
//  k = ks*32 + q*8 + jj, lane = q*16 + c16).
// Also: swizzled W_out (256x32, cols>=24 zero) and b_x = b_in@W_ih + b_ih.
// ---------------------------------------------------------------------------
__global__ void prep_kernel(const float* __restrict__ W_in, const float* __restrict__ b_in,
                            const float* __restrict__ W_ih, const float* __restrict__ b_ih,
                            const float* __restrict__ W_hh, const float* __restrict__ W_out,
                            unsigned short* __restrict__ wsW, unsigned short* __restrict__ wsWo,
                            float* __restrict__ wsBx) {
    int idx = blockIdx.x * 256 + threadIdx.x;
    if (idx < KDIM * NGATE) {
        int k = idx / NGATE, n = idx - k * NGATE;
        float s;
        if (k < OBS_DIMM) {
            s = 0.f;
            for (int j = 0; j < PROJJ; ++j) s += W_in[k * PROJJ + j] * W_ih[j * NGATE + n];
        } else {
            s = W_hh[(k - OBS_DIMM) * NGATE + n];
        }
        int ks = k >> 5, q = (k >> 3) & 3, jj = k & 7;
        int g = n >> 8, u = n & 255, w = u >> 5, i = (u >> 4) & 1, c16 = u & 15;
        int lane = q * 16 + c16;
        wsW[((w * 12 + ks) * 6 + i * 3 + g) * 512 + lane * 8 + jj] = f2bf(s);
    } else if (idx < KDIM * NGATE + 256 * 32) {
        int i2 = idx - KDIM * NGATE;
        int k = i2 >> 5, n = i2 & 31;
        float s = (n < LATT) ? W_out[k * LATT + n] : 0.f;
        int nt = n >> 4, nl = n & 15, ks = k >> 5, q = (k >> 3) & 3, jj = k & 7;
        wsWo[(nt * 8 + ks) * 512 + (q * 16 + nl) * 8 + jj] = f2bf(s);
    } else if (idx < KDIM * NGATE + 256 * 32 + NGATE) {
        int n = idx - (KDIM * NGATE + 256 * 32);
        float s = b_ih[n];
        for (int j = 0; j < PROJJ; ++j) s += b_in[j] * W_ih[j * NGATE + n];
        wsBx[n] = s;
    }
}

// ---------------------------------------------------------------------------
// Main: grid = 32 batch-groups x 8 time-chunks. Backtrack to last reset, roll
// forward, fused mish+W_out epilogue with LDS-staged coalesced output flush.
// Weight stream: per-wave sequential, depth-3 software pipeline in registers.
// ---------------------------------------------------------------------------
__global__ __launch_bounds__(512, 2)
void gru_kernel(const float* __restrict__ obs, const int* __restrict__ is_init,
                const float* __restrict__ hx, const float* __restrict__ b_hh,
                const float* __restrict__ b_out,
                const unsigned short* __restrict__ wsW, const unsigned short* __restrict__ wsWo,
                const float* __restrict__ wsBx,
                float* __restrict__ out, float* __restrict__ hfin) {
    __shared__ __align__(16) unsigned short sX[MBLK * XSTRIDE];   // [obs_t bf16 | h bf16]
    __shared__ __align__(16) unsigned short sM[MBLK * MSTRIDE];   // mish(h_new) bf16
    __shared__ __align__(16) unsigned short sWo[16 * 512];        // W_out fragments
    __shared__ __align__(16) float sOut[4 * MBLK * LATT];         // 4-step output stage
    __shared__ int sT;

    const int tid  = threadIdx.x;
    const int w    = tid >> 6;
    const int lane = tid & 63;
    const int q    = lane >> 4;
    const int c16  = lane & 15;
    const int bid  = blockIdx.x;
    const int g    = bid & 31;
    const int ch   = bid >> 5;
    const int b0   = g * MBLK;
    const int t0   = ch * CHUNK;

    // stage W_out fragments into LDS (8192 ushorts, 16 per thread)
    {
        const uint4* src = (const uint4*)(wsWo);
        uint4* dst = (uint4*)(sWo);
        dst[tid * 2]     = src[tid * 2];
        dst[tid * 2 + 1] = src[tid * 2 + 1];
    }

    // per-wave biases (col = (2w+i)*16 + c16)
    float bR[2], bZ[2], bXN[2], bHN[2];
#pragma unroll
    for (int i = 0; i < 2; ++i) {
        int u = (2 * w + i) * 16 + c16;
        bR[i]  = wsBx[u] + b_hh[u];
        bZ[i]  = wsBx[HIDD + u] + b_hh[HIDD + u];
        bXN[i] = wsBx[2 * HIDD + u];
        bHN[i] = b_hh[2 * HIDD + u];
    }
    float bOutV = 0.f;
    if (w < 4) {
        int col = (w & 1) * 16 + c16;
        bOutV = (col < LATT) ? b_out[col] : 0.f;
    }

    // ---- find start time: most recent reset before t0 (min over group) ----
    if (tid == 0) sT = (ch == 0) ? 0 : 0x7fffffff;
    __syncthreads();
    if (ch > 0 && tid < MBLK) {
        int b = b0 + tid, fs = 0;
        for (int t = t0 - 1; t > 0; --t) {
            if (is_init[b * TTIME + t] != 0) { fs = t; break; }
        }
        atomicMin(&sT, fs);
    }
    __syncthreads();
    const int tstart = sT;

    // ---- init hidden part of X: hx if starting at t=0, else 0
    {
        int bl = tid >> 4, part = tid & 15;
        bf16x8 v0 = {0, 0, 0, 0, 0, 0, 0, 0}, v1 = {0, 0, 0, 0, 0, 0, 0, 0};
        if (tstart == 0) {
            const float* hp = hx + (size_t)(b0 + bl) * HIDD + part * 16;
#pragma unroll
            for (int ii = 0; ii < 8; ++ii) {
                v0[ii] = (short)f2bf(hp[ii]);
                v1[ii] = (short)f2bf(hp[8 + ii]);
            }
        }
        *(bf16x8*)(sX + bl * XSTRIDE + OBS_DIMM + part * 16)     = v0;
        *(bf16x8*)(sX + bl * XSTRIDE + OBS_DIMM + part * 16 + 8) = v1;
    }
    __syncthreads();

    const unsigned short* wb = wsW + (size_t)w * 36864 + lane * 8;  // per-wave stream base
    const int tend = t0 + CHUNK;

    for (int t = tstart; t < tend; ++t) {
        // ---- weight pipeline prologue: issue slices 0..2 (oldest in queue;
        //      they complete during phase-1 staging / barrier drain)
        bf16x8 F[4][6];
#pragma unroll
        for (int d = 0; d < 3; ++d)
#pragma unroll
            for (int j = 0; j < 6; ++j)
                F[d][j] = *(const bf16x8*)(wb + (d * 6 + j) * 512);

        // ---- phase 1: stage obs_t (bf16, nontemporal) into X; reset-mask h
        {
            int bl = tid >> 4, part = tid & 15;
            const float* op = obs + ((size_t)((b0 + bl) * TTIME + t)) * OBS_DIMM + part * 8;
            f32x4v a = __builtin_nontemporal_load((const f32x4v*)op);
            f32x4v b = __builtin_nontemporal_load((const f32x4v*)(op + 4));
            bf16x8 pk;
            pk[0] = (short)f2bf(a[0]); pk[1] = (short)f2bf(a[1]);
            pk[2] = (short)f2bf(a[2]); pk[3] = (short)f2bf(a[3]);
            pk[4] = (short)f2bf(b[0]); pk[5] = (short)f2bf(b[1]);
            pk[6] = (short)f2bf(b[2]); pk[7] = (short)f2bf(b[3]);
            *(bf16x8*)(sX + bl * XSTRIDE + part * 8) = pk;
            if (is_init[(b0 + bl) * TTIME + t] != 0) {
                bf16x8 z8 = {0, 0, 0, 0, 0, 0, 0, 0};
                *(bf16x8*)(sX + bl * XSTRIDE + OBS_DIMM + part * 16)     = z8;
                *(bf16x8*)(sX + bl * XSTRIDE + OBS_DIMM + part * 16 + 8) = z8;
            }
        }
        __syncthreads();

        // ---- phase 2: gates[32,768] = [obs|h] @ W' (K=384), n-gate split at k=128
        f32x4 accR[2][2], accZ[2][2], accXN[2][2], accHN[2][2];
#pragma unroll
        for (int mt = 0; mt < 2; ++mt)
#pragma unroll
            for (int i = 0; i < 2; ++i) {
                accR[mt][i]  = (f32x4){bR[i], bR[i], bR[i], bR[i]};
                accZ[mt][i]  = (f32x4){bZ[i], bZ[i], bZ[i], bZ[i]};
                accXN[mt][i] = (f32x4){bXN[i], bXN[i], bXN[i], bXN[i]};
                accHN[mt][i] = (f32x4){bHN[i], bHN[i], bHN[i], bHN[i]};
            }
#pragma unroll
        for (int ks = 0; ks < 12; ++ks) {
            const int d = ks & 3;
            if (ks < 9) {                       // prefetch slice ks+3 (depth 3)
                const int dn = (ks + 3) & 3;
#pragma unroll
                for (int j = 0; j < 6; ++j)
                    F[dn][j] = *(const bf16x8*)(wb + ((ks + 3) * 6 + j) * 512);
            }
            bf16x8 a0 = *(const bf16x8*)(sX + c16 * XSTRIDE + ks * 32 + q * 8);
            bf16x8 a1 = *(const bf16x8*)(sX + (16 + c16) * XSTRIDE + ks * 32 + q * 8);
#pragma unroll
            for (int i = 0; i < 2; ++i) {
                accR[0][i] = MFMA16(a0, F[d][i * 3 + 0], accR[0][i]);
                accR[1][i] = MFMA16(a1, F[d][i * 3 + 0], accR[1][i]);
                accZ[0][i] = MFMA16(a0, F[d][i * 3 + 1], accZ[0][i]);
                accZ[1][i] = MFMA16(a1, F[d][i * 3 + 1], accZ[1][i]);
                if (ks < 4) {
                    accXN[0][i] = MFMA16(a0, F[d][i * 3 + 2], accXN[0][i]);
                    accXN[1][i] = MFMA16(a1, F[d][i * 3 + 2], accXN[1][i]);
                } else {
                    accHN[0][i] = MFMA16(a0, F[d][i * 3 + 2], accHN[0][i]);
                    accHN[1][i] = MFMA16(a1, F[d][i * 3 + 2], accHN[1][i]);
                }
            }
        }
        __syncthreads();  // A-frag reads of X done before h is overwritten

        // ---- phase 3: wave-local gates + h update (+ mish only when needed)
        const bool emit = (t >= t0);
#pragma unroll
        for (int mt = 0; mt < 2; ++mt)
#pragma unroll
            for (int i = 0; i < 2; ++i) {
                int u = (2 * w + i) * 16 + c16;
#pragma unroll
                for (int r = 0; r < 4; ++r) {
                    int bl = mt * 16 + q * 4 + r;
                    float rr = sigmoid_(accR[mt][i][r]);
                    float zz = sigmoid_(accZ[mt][i][r]);
                    float nn = tanh_(accXN[mt][i][r] + rr * accHN[mt][i][r]);
                    float hOld = bf2f(sX[bl * XSTRIDE + OBS_DIMM + u]);
                    float hN = (1.f - zz) * nn + zz * hOld;
                    sX[bl * XSTRIDE + OBS_DIMM + u] = f2bf(hN);
                    if (emit) {
                        float sp = 0.69314718f * flog2(1.f + fexp2(1.44269504f * hN));
                        sM[bl * MSTRIDE + u] = f2bf(hN * tanh_(sp));
                    }
                }
            }
        __syncthreads();  // mish + h_new visible

        // ---- phase 4: out-tile GEMM into LDS stage (waves 0..3, own chunk only)
        if (emit && w < 4) {
            int mto = w >> 1, nto = w & 1;
            f32x4 acc = (f32x4){bOutV, bOutV, bOutV, bOutV};
#pragma unroll
            for (int ks = 0; ks < 8; ++ks) {
                bf16x8 a  = *(const bf16x8*)(sM + (mto * 16 + c16) * MSTRIDE + ks * 32 + q * 8);
                bf16x8 wf = *(const bf16x8*)(sWo + (nto * 8 + ks) * 512 + lane * 8);
                acc = MFMA16(a, wf, acc);
            }
            int col = nto * 16 + c16;
            if (col < LATT) {
                int dt = (t - t0) & 3;
#pragma unroll
                for (int r = 0; r < 4; ++r) {
                    int bl = mto * 16 + q * 4 + r;
                    sOut[(dt * MBLK + bl) * LATT + col] = acc[r];
                }
            }
        }

        // ---- flush 4 staged timesteps as coalesced nontemporal lines
        if (emit && ((t - t0) & 3) == 3) {
            __syncthreads();
            int tf = t - 3;
#pragma unroll
            for (int p = 0; p < 6; ++p) {
                int v = p * 512 + tid;            // 0..3071
                int b = v / 96, rr = v - 96 * b;  // rr = dt*24 + col
                int dt = rr / 24, col = rr - 24 * dt;
                float val = sOut[(dt * MBLK + b) * LATT + col];
                __builtin_nontemporal_store(val,
                    out + ((size_t)(b0 + b) * TTIME + tf + dt) * LATT + col);
            }
        }
    }

    // ---- h_final from the last chunk's blocks (ordered by the final flush barrier)
    if (ch == 7) {
#pragma unroll
        for (int ii = 0; ii < 16; ++ii) {
            int v = tid * 16 + ii;
            int bl = v >> 8, u = v & 255;
            hfin[(size_t)(b0 + bl) * HIDD + u] = bf2f(sX[bl * XSTRIDE + OBS_DIMM + u]);
        }
    }
}

extern "C" void kernel_launch(void* const* d_in, const int* in_sizes, int n_in,
                              void* d_out, int out_size, void* d_ws, size_t ws_size,
                              hipStream_t stream) {
    const float* obs    = (const float*)d_in[0];
    const int*   isini  = (const int*)d_in[1];
    const float* hx     = (const float*)d_in[2];
    const float* W_in   = (const float*)d_in[3];
    const float* b_in   = (const float*)d_in[4];
    const float* W_ih   = (const float*)d_in[5];
    const float* b_ih   = (const float*)d_in[6];
    const float* W_hh   = (const float*)d_in[7];
    const float* b_hh   = (const float*)d_in[8];
    const float* W_out  = (const float*)d_in[9];
    const float* b_out  = (const float*)d_in[10];

    // workspace layout: W' bf16 | W_out' bf16 | b_x f32
    unsigned short* wsW  = (unsigned short*)d_ws;
    unsigned short* wsWo = wsW + KDIM * NGATE;        // 294912 elems
    float*          wsBx = (float*)(wsWo + 256 * 32); // 8192 elems

    float* outp = (float*)d_out;
    float* hfin = outp + (size_t)BBATCH * TTIME * LATT;

    prep_kernel<<<1187, 256, 0, stream>>>(W_in, b_in, W_ih, b_ih, W_hh, W_out, wsW, wsWo, wsBx);
    gru_kernel<<<256, 512, 0, stream>>>(obs, isini, hx, b_hh, b_out, wsW, wsWo, wsBx, outp, hfin);
}